// Round 4
// baseline (1643.151 us; speedup 1.0000x reference)
//
#include <hip/hip_runtime.h>

#define BATCH 8
#define CCH 256
#define NPOS 4096
#define LOG2E 1.4426950408889634f

typedef __bf16 bf16x8 __attribute__((ext_vector_type(8)));
typedef float f32x4 __attribute__((ext_vector_type(4)));
typedef float f32x2 __attribute__((ext_vector_type(2)));
typedef int i32x4 __attribute__((ext_vector_type(4)));
typedef unsigned short us4 __attribute__((ext_vector_type(4)));

typedef const __attribute__((address_space(1))) void GAS;
typedef __attribute__((address_space(3))) void LAS;

#define CFENCE() __asm__ volatile("" ::: "memory")
// vmcnt(8), lgkmcnt no-wait(15), expcnt no-wait(7): (15<<8)|(7<<4)|8
#define WAIT_VM8()  do { CFENCE(); __builtin_amdgcn_s_waitcnt(0x0F78); CFENCE(); } while (0)
// lgkmcnt(0), vmcnt no-wait, expcnt no-wait
#define WAIT_LGKM0() do { CFENCE(); __builtin_amdgcn_s_waitcnt(0xC07F); CFENCE(); } while (0)
#define BAR_RAW() do { CFENCE(); __builtin_amdgcn_s_barrier(); CFENCE(); } while (0)

__device__ __forceinline__ unsigned short f2bf(float f) {
  unsigned u = __builtin_bit_cast(unsigned, f);
  u += 0x7fffu + ((u >> 16) & 1u);
  return (unsigned short)(u >> 16);
}
__device__ __forceinline__ bf16x8 ld_bf8(const unsigned short* p) {
  i32x4 t = *reinterpret_cast<const i32x4*>(p);
  return __builtin_bit_cast(bf16x8, t);
}

// ---------------------------------------------------------------- kernel 1
__global__ void cvt_kernel(const float* __restrict__ Wq,
                           const float* __restrict__ Wk,
                           const float* __restrict__ Wv,
                           unsigned short* __restrict__ dst)
{
  const int idx = blockIdx.x * 256 + threadIdx.x;   // 0..196607
  const float* src = (idx < 65536) ? Wq : ((idx < 131072) ? Wk : Wv);
  float v = src[idx & 65535];
  if (idx < 65536) v *= LOG2E;      // fold log2e into Q projection (exp2 softmax)
  dst[idx] = f2bf(v);
}

// ---------------------------------------------------------------- kernel 2
// One block per (b, 64-pos tile); z-loop over 4 o-phases reuses staged xT.
__global__ __launch_bounds__(256, 3)
void qkv_kernel(const float* __restrict__ x,
                const unsigned short* __restrict__ Wall,   // Wq*log2e|Wk|Wv bf16
                const float* __restrict__ bq,
                const float* __restrict__ bk,
                const float* __restrict__ bv,
                unsigned short* __restrict__ qT,
                unsigned short* __restrict__ kT,
                unsigned short* __restrict__ vG)
{
  __shared__ __align__(16) unsigned short xT[64 * 264];   // 33792 B
  __shared__ __align__(16) unsigned short tbuf[64 * 72];  //  9216 B (v transpose)

  const int b   = blockIdx.x;
  const int i0  = blockIdx.y * 64;
  const int tid = threadIdx.x;
  const int w   = tid >> 6;
  const int l   = tid & 63;
  const int n   = l & 15;
  const int q4  = l >> 4;

  // stage x tile: thread = channel, float4 over positions
  {
    const float* xp = x + ((size_t)b * CCH + tid) * NPOS + i0;
#pragma unroll
    for (int it = 0; it < 16; ++it) {
      f32x4 f = *reinterpret_cast<const f32x4*>(xp + it * 4);
#pragma unroll
      for (int e = 0; e < 4; ++e) xT[(it * 4 + e) * 264 + tid] = f2bf(f[e]);
    }
  }
  __syncthreads();

  const size_t qbase = (size_t)b * NPOS * CCH;

  for (int z = 0; z < 4; ++z) {
    const int obase = z * 64;
    for (int s = 0; s < 3; ++s) {
      const unsigned short* Wp = Wall + s * 65536 + (size_t)(obase + w * 16 + n) * CCH + q4 * 8;
      bf16x8 wfr[8];
#pragma unroll
      for (int kk = 0; kk < 8; ++kk) wfr[kk] = ld_bf8(Wp + kk * 32);

      const float* bias = (s == 0) ? bq : (s == 1) ? bk : bv;
      const float bscale = (s == 0) ? LOG2E : 1.0f;
      float bo[4];
#pragma unroll
      for (int r = 0; r < 4; ++r) bo[r] = bias[obase + w * 16 + q4 * 4 + r] * bscale;

      f32x4 acc[4];
#pragma unroll
      for (int pt = 0; pt < 4; ++pt) {
        acc[pt] = {0.f, 0.f, 0.f, 0.f};
#pragma unroll
        for (int kk = 0; kk < 8; ++kk) {
          bf16x8 bfr = ld_bf8(&xT[(pt * 16 + n) * 264 + kk * 32 + q4 * 8]);
          acc[pt] = __builtin_amdgcn_mfma_f32_16x16x32_bf16(wfr[kk], bfr, acc[pt], 0, 0, 0);
        }
      }

      if (s < 2) {
        unsigned short* dst = (s == 0 ? qT : kT) + qbase;
#pragma unroll
        for (int pt = 0; pt < 4; ++pt) {
          us4 pk = { f2bf(acc[pt][0] + bo[0]), f2bf(acc[pt][1] + bo[1]),
                     f2bf(acc[pt][2] + bo[2]), f2bf(acc[pt][3] + bo[3]) };
          *reinterpret_cast<us4*>(&dst[(size_t)(i0 + pt * 16 + n) * CCH + obase + w * 16 + q4 * 4]) = pk;
        }
      } else {
        __syncthreads();   // tbuf free (previous z's v-store consumed it)
#pragma unroll
        for (int pt = 0; pt < 4; ++pt)
#pragma unroll
          for (int r = 0; r < 4; ++r)
            tbuf[(w * 16 + q4 * 4 + r) * 72 + pt * 16 + n] = f2bf(acc[pt][r] + bo[r]);
        __syncthreads();
#pragma unroll
        for (int it = 0; it < 2; ++it) {
          const int idx = it * 256 + tid;
          const int o = idx >> 3, pw = (idx & 7) * 8;
          i32x4 d = *reinterpret_cast<const i32x4*>(&tbuf[o * 72 + pw]);
          *reinterpret_cast<i32x4*>(&vG[qbase + (size_t)(obase + o) * NPOS + i0 + pw]) = d;
        }
      }
    }
  }
}

// ---------------------------------------------------------------- kernel 3
// Flash attention, Br=64, Bc=64, 4 waves.
//  - K staged via global_load_lds (width 16) into XOR-swizzled double buffer
//    (R3 lesson: per-lane global K reads -> 20x HBM overfetch, L2 thrash)
//  - 2x2 wave split in S: wave (ig,jh) computes 32i x 32j -> each K B-frag
//    reused for 2 Q A-frag sets (halves S-phase LDS reads)
//  - cross-wave softmax max-combine via 128-float LDS exchange (broadcast reads)
//  - P in XOR-swizzled pbuf (measured 0 bank conflicts in R3)
//  - exp2-domain softmax (log2e folded into Wq/bq); l via ones-MFMA
//  - V per-lane b128 from global, prefetched at iter top; 3 raw barriers/iter,
//    explicit vmcnt(8): K[jt+1] DMA stays in flight across softmax+PV
__global__ __launch_bounds__(256, 2)
void attn_kernel(const unsigned short* __restrict__ qT,
                 const unsigned short* __restrict__ kT,
                 const unsigned short* __restrict__ vG,
                 const float* __restrict__ x,
                 const float* __restrict__ gamma,
                 float* __restrict__ out)
{
  __shared__ __align__(16) unsigned short kbuf[2][64 * 256];  // 2 x 32768 B, swizzled
  __shared__ __align__(16) unsigned short pbuf[64 * 64];      //  8192 B, swizzled
  __shared__ __align__(8) float pstat[64 * 2];                //  partial max [i][jh]
  __shared__ float stat_lds[64];                              //  alpha / l broadcast

  const int b   = blockIdx.x;
  const int i0  = blockIdx.y * 64;
  const int tid = threadIdx.x;
  const int w   = tid >> 6;
  const int l   = tid & 63;
  const int n   = l & 15;
  const int q4  = l >> 4;
  const int nsw = n & 7;
  const int ig  = w >> 1;      // i-half owner (32 rows)
  const int jh  = w & 1;       // j-half owner (32 cols)

  const unsigned short* qTb = qT + (size_t)b * NPOS * CCH;
  const unsigned short* kTb = kT + (size_t)b * NPOS * CCH;
  const unsigned short* vb  = vG + (size_t)b * NPOS * CCH;

  // Q fragments register-resident: 2 sets of 8 (rows ig*32 + it2*16 + n)
  bf16x8 afr[2][8];
#pragma unroll
  for (int it2 = 0; it2 < 2; ++it2) {
    const unsigned short* qrow = qTb + (size_t)(i0 + ig * 32 + it2 * 16 + n) * CCH + q4 * 8;
#pragma unroll
    for (int kk = 0; kk < 8; ++kk) afr[it2][kk] = ld_bf8(qrow + kk * 32);
  }
  bf16x8 ones;
  {
    i32x4 t = { (int)0x3F803F80, (int)0x3F803F80, (int)0x3F803F80, (int)0x3F803F80 };
    ones = __builtin_bit_cast(bf16x8, t);
  }

  // stage K[0]: wave issues 8 DMA loads; instr t covers local rows 2t,2t+1.
  // phys granule gp at row j holds logical granule gp ^ (j&7).
#pragma unroll
  for (int it = 0; it < 8; ++it) {
    const int t = w * 8 + it;
    const int j = 2 * t + (l >> 5);
    const int gp = l & 31;
    const int g  = gp ^ (j & 7);
    const unsigned short* src = kTb + (size_t)j * CCH + g * 8;
    unsigned short* dst = &kbuf[0][t * 512];
    __builtin_amdgcn_global_load_lds((GAS*)src, (LAS*)dst, 16, 0, 0);
  }

  f32x4 O[16];   // [ct*4+it]: c in [w*64+ct*16,+16), i in [it*16,+16)
#pragma unroll
  for (int t = 0; t < 16; ++t) O[t] = {0.f, 0.f, 0.f, 0.f};
  f32x4 lacc = {0.f, 0.f, 0.f, 0.f};
  float mrow[2][4] = {{-1e30f, -1e30f, -1e30f, -1e30f}, {-1e30f, -1e30f, -1e30f, -1e30f}};

  for (int jt = 0; jt < 64; ++jt) {
    const int j0 = jt * 64;
    const unsigned short* kb = kbuf[jt & 1];

    // prefetch V[jt] into registers (always the 8 NEWEST vmem ops)
    i32x4 vreg[8];
#pragma unroll
    for (int ct = 0; ct < 4; ++ct) {
      const unsigned short* vp = vb + (size_t)(w * 64 + ct * 16 + n) * NPOS + j0 + q4 * 8;
      vreg[ct * 2]     = *reinterpret_cast<const i32x4*>(vp);
      vreg[ct * 2 + 1] = *reinterpret_cast<const i32x4*>(vp + 32);
    }

    WAIT_VM8();     // drain everything older than V[jt] => K[jt] DMA complete
    BAR_RAW();      // BAR A: K[jt] in LDS for all; pstat/pbuf free

    // ---- S (2x2): wave computes i in [ig*32,+32), j in [jh*32,+32)
    f32x4 sacc[2][2];
#pragma unroll
    for (int a = 0; a < 2; ++a)
#pragma unroll
      for (int c = 0; c < 2; ++c) sacc[a][c] = {0.f, 0.f, 0.f, 0.f};
    {
      const unsigned short* r0 = kb + (jh * 32 + n) * 256;
      const unsigned short* r1 = kb + (jh * 32 + 16 + n) * 256;
#pragma unroll
      for (int kk = 0; kk < 8; ++kk) {
        const int gp = ((kk * 4 + q4) ^ nsw) * 8;
        bf16x8 b0 = ld_bf8(r0 + gp);
        bf16x8 b1 = ld_bf8(r1 + gp);
        sacc[0][0] = __builtin_amdgcn_mfma_f32_16x16x32_bf16(afr[0][kk], b0, sacc[0][0], 0, 0, 0);
        sacc[1][0] = __builtin_amdgcn_mfma_f32_16x16x32_bf16(afr[1][kk], b0, sacc[1][0], 0, 0, 0);
        sacc[0][1] = __builtin_amdgcn_mfma_f32_16x16x32_bf16(afr[0][kk], b1, sacc[0][1], 0, 0, 0);
        sacc[1][1] = __builtin_amdgcn_mfma_f32_16x16x32_bf16(afr[1][kk], b1, sacc[1][1], 0, 0, 0);
      }
    }

    // ---- partial row max over this wave's 32 j
#pragma unroll
    for (int it2 = 0; it2 < 2; ++it2) {
      float pm[4];
#pragma unroll
      for (int r = 0; r < 4; ++r) {
        float tm = fmaxf(sacc[it2][0][r], sacc[it2][1][r]);
        tm = fmaxf(tm, __shfl_xor(tm, 1));
        tm = fmaxf(tm, __shfl_xor(tm, 2));
        tm = fmaxf(tm, __shfl_xor(tm, 4));
        tm = fmaxf(tm, __shfl_xor(tm, 8));
        pm[r] = tm;
      }
      if (n == 0) {
#pragma unroll
        for (int r = 0; r < 4; ++r)
          pstat[(ig * 32 + it2 * 16 + q4 * 4 + r) * 2 + jh] = pm[r];
      }
    }

    WAIT_LGKM0();
    BAR_RAW();      // BAR B: both halves' partial maxima visible

    // ---- combine maxima, exp, write P + alpha
#pragma unroll
    for (int it2 = 0; it2 < 2; ++it2) {
#pragma unroll
      for (int r = 0; r < 4; ++r) {
        const int i = ig * 32 + it2 * 16 + q4 * 4 + r;
        const f32x2 pp = *reinterpret_cast<const f32x2*>(&pstat[i * 2]);   // broadcast
        const float tm = fmaxf(pp[0], pp[1]);
        const float mnew = fmaxf(mrow[it2][r], tm);
        const float a = __builtin_amdgcn_exp2f(mrow[it2][r] - mnew);
        mrow[it2][r] = mnew;
        if (jh == 0 && n == 0) stat_lds[i] = a;
        const int r7 = i & 7;
#pragma unroll
        for (int jt2 = 0; jt2 < 2; ++jt2) {
          const float p = __builtin_amdgcn_exp2f(sacc[it2][jt2][r] - mnew);
          const int chunk = jh * 4 + jt2 * 2 + (n >> 3);
          pbuf[i * 64 + (chunk ^ r7) * 8 + nsw] = f2bf(p);
        }
      }
    }

    // ---- prefetch K[jt+1] DMA (unconditional, wrapped)
    {
      const int j0n = ((jt + 1) & 63) * 64;
      unsigned short* bufn = kbuf[(jt + 1) & 1];
#pragma unroll
      for (int it = 0; it < 8; ++it) {
        const int t = w * 8 + it;
        const int j = 2 * t + (l >> 5);
        const int gp = l & 31;
        const int g  = gp ^ (j & 7);
        const unsigned short* src = kTb + (size_t)(j0n + j) * CCH + g * 8;
        unsigned short* dst = &bufn[t * 512];
        __builtin_amdgcn_global_load_lds((GAS*)src, (LAS*)dst, 16, 0, 0);
      }
    }

    WAIT_LGKM0();
    BAR_RAW();      // BAR C: P + alpha visible; K' DMA still in flight

    // ---- rescale O by alpha; PV (V regs, P from LDS); l via ones-MFMA
    float al[4];
#pragma unroll
    for (int it = 0; it < 4; ++it) al[it] = stat_lds[it * 16 + n];

    bf16x8 pf[8];
#pragma unroll
    for (int it = 0; it < 4; ++it) {
      const int rw = it * 16 + n;
      const int r7 = rw & 7;
      pf[it * 2 + 0] = ld_bf8(&pbuf[rw * 64 + ((q4) ^ r7) * 8]);
      pf[it * 2 + 1] = ld_bf8(&pbuf[rw * 64 + ((4 + q4) ^ r7) * 8]);
    }

#pragma unroll
    for (int it = 0; it < 4; ++it) {
#pragma unroll
      for (int ct = 0; ct < 4; ++ct) {
        f32x4& o = O[ct * 4 + it];
        o[0] *= al[it]; o[1] *= al[it]; o[2] *= al[it]; o[3] *= al[it];
      }
    }
    lacc[0] *= al[w]; lacc[1] *= al[w]; lacc[2] *= al[w]; lacc[3] *= al[w];
    lacc = __builtin_amdgcn_mfma_f32_16x16x32_bf16(ones, pf[w * 2 + 0], lacc, 0, 0, 0);
    lacc = __builtin_amdgcn_mfma_f32_16x16x32_bf16(ones, pf[w * 2 + 1], lacc, 0, 0, 0);

#pragma unroll
    for (int ct = 0; ct < 4; ++ct) {
      bf16x8 vf0 = __builtin_bit_cast(bf16x8, vreg[ct * 2]);
      bf16x8 vf1 = __builtin_bit_cast(bf16x8, vreg[ct * 2 + 1]);
#pragma unroll
      for (int it = 0; it < 4; ++it) {
        O[ct * 4 + it] = __builtin_amdgcn_mfma_f32_16x16x32_bf16(vf0, pf[it * 2 + 0], O[ct * 4 + it], 0, 0, 0);
        O[ct * 4 + it] = __builtin_amdgcn_mfma_f32_16x16x32_bf16(vf1, pf[it * 2 + 1], O[ct * 4 + it], 0, 0, 0);
      }
    }
  }

  // ---- epilogue: y = x + gamma * O / l
  __syncthreads();
  if (q4 == 0) stat_lds[w * 16 + n] = lacc[0];
  __syncthreads();
  const float g = gamma[0];
#pragma unroll
  for (int it = 0; it < 4; ++it) {
    const float sc = g / stat_lds[it * 16 + n];
    const int ipos = i0 + it * 16 + n;
#pragma unroll
    for (int ct = 0; ct < 4; ++ct) {
#pragma unroll
      for (int r = 0; r < 4; ++r) {
        const int c = w * 64 + ct * 16 + q4 * 4 + r;
        const size_t idx = ((size_t)(b * CCH + c)) * NPOS + ipos;
        out[idx] = x[idx] + sc * O[ct * 4 + it][r];
      }
    }
  }
}

// ---------------------------------------------------------------- launch
extern "C" void kernel_launch(void* const* d_in, const int* in_sizes, int n_in,
                              void* d_out, int out_size, void* d_ws, size_t ws_size,
                              hipStream_t stream)
{
  const float* x     = (const float*)d_in[0];
  const float* Wq    = (const float*)d_in[1];
  const float* bq    = (const float*)d_in[2];
  const float* Wk    = (const float*)d_in[3];
  const float* bk    = (const float*)d_in[4];
  const float* Wv    = (const float*)d_in[5];
  const float* bv    = (const float*)d_in[6];
  const float* gamma = (const float*)d_in[7];
  float* out = (float*)d_out;

  unsigned short* ws   = (unsigned short*)d_ws;
  unsigned short* Wall = ws;                                  // 3 x 65536 bf16
  unsigned short* qT   = ws + 196608;                         // (B,N,C) bf16
  unsigned short* kT   = qT + (size_t)BATCH * NPOS * CCH;     // (B,N,C) bf16
  unsigned short* vG   = kT + (size_t)BATCH * NPOS * CCH;     // (B,C,N) bf16

  cvt_kernel<<<768, 256, 0, stream>>>(Wq, Wk, Wv, Wall);
  qkv_kernel<<<dim3(8, 64), 256, 0, stream>>>(x, Wall, bq, bk, bv, qT, kT, vG);
  attn_kernel<<<dim3(8, 64), 256, 0, stream>>>(qT, kT, vG, x, gamma, out);
}

// Round 6
// 1543.468 us; speedup vs baseline: 1.0646x; 1.0646x over previous
//
#include <hip/hip_runtime.h>

#define BATCH 8
#define CCH 256
#define NPOS 4096
#define LOG2E 1.4426950408889634f

typedef __bf16 bf16x8 __attribute__((ext_vector_type(8)));
typedef float f32x4 __attribute__((ext_vector_type(4)));
typedef float f32x2 __attribute__((ext_vector_type(2)));
typedef int i32x4 __attribute__((ext_vector_type(4)));
typedef unsigned short us4 __attribute__((ext_vector_type(4)));

typedef const __attribute__((address_space(1))) void GAS;
typedef __attribute__((address_space(3))) void LAS;

#define CFENCE() __asm__ volatile("" ::: "memory")
// vmcnt(0), lgkm no-wait(15), exp no-wait(7)
#define WAIT_VM0()  do { CFENCE(); __builtin_amdgcn_s_waitcnt(0x0F70); CFENCE(); } while (0)
// lgkmcnt(0), vmcnt no-wait(63), exp no-wait
#define WAIT_LGKM0() do { CFENCE(); __builtin_amdgcn_s_waitcnt(0xC07F); CFENCE(); } while (0)
#define BAR_RAW() do { CFENCE(); __builtin_amdgcn_s_barrier(); CFENCE(); } while (0)

__device__ __forceinline__ unsigned short f2bf(float f) {
  unsigned u = __builtin_bit_cast(unsigned, f);
  u += 0x7fffu + ((u >> 16) & 1u);
  return (unsigned short)(u >> 16);
}
__device__ __forceinline__ bf16x8 ld_bf8(const unsigned short* p) {
  i32x4 t = *reinterpret_cast<const i32x4*>(p);
  return __builtin_bit_cast(bf16x8, t);
}

// ---------------------------------------------------------------- kernel 1
__global__ void cvt_kernel(const float* __restrict__ Wq,
                           const float* __restrict__ Wk,
                           const float* __restrict__ Wv,
                           unsigned short* __restrict__ dst)
{
  const int idx = blockIdx.x * 256 + threadIdx.x;   // 0..196607
  const float* src = (idx < 65536) ? Wq : ((idx < 131072) ? Wk : Wv);
  float v = src[idx & 65535];
  if (idx < 65536) v *= LOG2E;      // fold log2e into Q projection (exp2 softmax)
  dst[idx] = f2bf(v);
}

// ---------------------------------------------------------------- kernel 2
// One block per (b, 64-pos tile); z-loop over 4 o-phases reuses staged xT.
// (R3-measured: cvt+qkv ~57 us)
__global__ __launch_bounds__(256, 3)
void qkv_kernel(const float* __restrict__ x,
                const unsigned short* __restrict__ Wall,   // Wq*log2e|Wk|Wv bf16
                const float* __restrict__ bq,
                const float* __restrict__ bk,
                const float* __restrict__ bv,
                unsigned short* __restrict__ qT,
                unsigned short* __restrict__ kT,
                unsigned short* __restrict__ vG)
{
  __shared__ __align__(16) unsigned short xT[64 * 264];   // 33792 B
  __shared__ __align__(16) unsigned short tbuf[64 * 72];  //  9216 B (v transpose)

  const int b   = blockIdx.x;
  const int i0  = blockIdx.y * 64;
  const int tid = threadIdx.x;
  const int w   = tid >> 6;
  const int l   = tid & 63;
  const int n   = l & 15;
  const int q4  = l >> 4;

  {
    const float* xp = x + ((size_t)b * CCH + tid) * NPOS + i0;
#pragma unroll
    for (int it = 0; it < 16; ++it) {
      f32x4 f = *reinterpret_cast<const f32x4*>(xp + it * 4);
#pragma unroll
      for (int e = 0; e < 4; ++e) xT[(it * 4 + e) * 264 + tid] = f2bf(f[e]);
    }
  }
  __syncthreads();

  const size_t qbase = (size_t)b * NPOS * CCH;

  for (int z = 0; z < 4; ++z) {
    const int obase = z * 64;
    for (int s = 0; s < 3; ++s) {
      const unsigned short* Wp = Wall + s * 65536 + (size_t)(obase + w * 16 + n) * CCH + q4 * 8;
      bf16x8 wfr[8];
#pragma unroll
      for (int kk = 0; kk < 8; ++kk) wfr[kk] = ld_bf8(Wp + kk * 32);

      const float* bias = (s == 0) ? bq : (s == 1) ? bk : bv;
      const float bscale = (s == 0) ? LOG2E : 1.0f;
      float bo[4];
#pragma unroll
      for (int r = 0; r < 4; ++r) bo[r] = bias[obase + w * 16 + q4 * 4 + r] * bscale;

      f32x4 acc[4];
#pragma unroll
      for (int pt = 0; pt < 4; ++pt) {
        acc[pt] = {0.f, 0.f, 0.f, 0.f};
#pragma unroll
        for (int kk = 0; kk < 8; ++kk) {
          bf16x8 bfr = ld_bf8(&xT[(pt * 16 + n) * 264 + kk * 32 + q4 * 8]);
          acc[pt] = __builtin_amdgcn_mfma_f32_16x16x32_bf16(wfr[kk], bfr, acc[pt], 0, 0, 0);
        }
      }

      if (s < 2) {
        unsigned short* dst = (s == 0 ? qT : kT) + qbase;
#pragma unroll
        for (int pt = 0; pt < 4; ++pt) {
          us4 pk = { f2bf(acc[pt][0] + bo[0]), f2bf(acc[pt][1] + bo[1]),
                     f2bf(acc[pt][2] + bo[2]), f2bf(acc[pt][3] + bo[3]) };
          *reinterpret_cast<us4*>(&dst[(size_t)(i0 + pt * 16 + n) * CCH + obase + w * 16 + q4 * 4]) = pk;
        }
      } else {
        __syncthreads();   // tbuf free (previous z's v-store consumed it)
#pragma unroll
        for (int pt = 0; pt < 4; ++pt)
#pragma unroll
          for (int r = 0; r < 4; ++r)
            tbuf[(w * 16 + q4 * 4 + r) * 72 + pt * 16 + n] = f2bf(acc[pt][r] + bo[r]);
        __syncthreads();
#pragma unroll
        for (int it = 0; it < 2; ++it) {
          const int idx = it * 256 + tid;
          const int o = idx >> 3, pw = (idx & 7) * 8;
          i32x4 d = *reinterpret_cast<const i32x4*>(&tbuf[o * 72 + pw]);
          *reinterpret_cast<i32x4*>(&vG[qbase + (size_t)(obase + o) * NPOS + i0 + pw]) = d;
        }
      }
    }
  }
}

// ---------------------------------------------------------------- kernel 3
// Flash attention, Br=64, Bc=64, 4 waves, 2x2 wave-split S phase.
// R5 = R4 dataflow with register lifetimes re-timed to avoid the R4 spill:
//  - V loads just-in-time in PV (2 chunks of 16 regs), not live across S
//  - K DMA prefetch issued mid-PV after last V chunk (vmcnt order: V retires
//    at vmcnt(10)/(8) without draining the 8 DMA ops)
//  - peak arch VGPRs ~120 (R4 was ~164 -> 1.4 GB scratch spill traffic)
__global__ __launch_bounds__(256, 2)
void attn_kernel(const unsigned short* __restrict__ qT,
                 const unsigned short* __restrict__ kT,
                 const unsigned short* __restrict__ vG,
                 const float* __restrict__ x,
                 const float* __restrict__ gamma,
                 float* __restrict__ out)
{
  __shared__ __align__(16) unsigned short kbuf[2][64 * 256];  // 2 x 32768 B, swizzled
  __shared__ __align__(16) unsigned short pbuf[64 * 64];      //  8192 B, swizzled
  __shared__ __align__(8) float pstat[64 * 2];                //  partial max [i][jh]
  __shared__ float stat_lds[64];                              //  alpha / l broadcast

  const int b   = blockIdx.x;
  const int i0  = blockIdx.y * 64;
  const int tid = threadIdx.x;
  const int w   = tid >> 6;
  const int l   = tid & 63;
  const int n   = l & 15;
  const int q4  = l >> 4;
  const int nsw = n & 7;
  const int ig  = w >> 1;      // i-half owner (32 rows)
  const int jh  = w & 1;       // j-half owner (32 cols)

  const unsigned short* qTb = qT + (size_t)b * NPOS * CCH;
  const unsigned short* kTb = kT + (size_t)b * NPOS * CCH;
  const unsigned short* vb  = vG + (size_t)b * NPOS * CCH;

  // Q fragments register-resident: 2 sets of 8 (rows ig*32 + it2*16 + n) = 64 VGPRs
  bf16x8 afr[2][8];
#pragma unroll
  for (int it2 = 0; it2 < 2; ++it2) {
    const unsigned short* qrow = qTb + (size_t)(i0 + ig * 32 + it2 * 16 + n) * CCH + q4 * 8;
#pragma unroll
    for (int kk = 0; kk < 8; ++kk) afr[it2][kk] = ld_bf8(qrow + kk * 32);
  }
  bf16x8 ones;
  {
    i32x4 t = { (int)0x3F803F80, (int)0x3F803F80, (int)0x3F803F80, (int)0x3F803F80 };
    ones = __builtin_bit_cast(bf16x8, t);
  }

  // stage K[0] DMA; phys granule gp at row j holds logical granule gp ^ (j&7)
#pragma unroll
  for (int it = 0; it < 8; ++it) {
    const int t = w * 8 + it;
    const int j = 2 * t + (l >> 5);
    const int gp = l & 31;
    const int g  = gp ^ (j & 7);
    const unsigned short* src = kTb + (size_t)j * CCH + g * 8;
    unsigned short* dst = &kbuf[0][t * 512];
    __builtin_amdgcn_global_load_lds((GAS*)src, (LAS*)dst, 16, 0, 0);
  }

  f32x4 O[16];   // [ct*4+it]: c in [w*64+ct*16,+16), i in [it*16,+16)
#pragma unroll
  for (int t = 0; t < 16; ++t) O[t] = {0.f, 0.f, 0.f, 0.f};
  f32x4 lacc = {0.f, 0.f, 0.f, 0.f};
  float mrow[2][4] = {{-1e30f, -1e30f, -1e30f, -1e30f}, {-1e30f, -1e30f, -1e30f, -1e30f}};

  for (int jt = 0; jt < 64; ++jt) {
    const int j0 = jt * 64;
    const unsigned short* kb = kbuf[jt & 1];

    WAIT_VM0();     // only K[jt] DMA is in flight here -> exact drain
    BAR_RAW();      // BAR A: K[jt] in LDS for all; all waves done prev PV

    // ---- S (2x2): wave computes i in [ig*32,+32), j in [jh*32,+32)
    f32x4 sacc[2][2];
#pragma unroll
    for (int a = 0; a < 2; ++a)
#pragma unroll
      for (int c = 0; c < 2; ++c) sacc[a][c] = {0.f, 0.f, 0.f, 0.f};
    {
      const unsigned short* r0 = kb + (jh * 32 + n) * 256;
      const unsigned short* r1 = kb + (jh * 32 + 16 + n) * 256;
#pragma unroll
      for (int kk = 0; kk < 8; ++kk) {
        const int gp = ((kk * 4 + q4) ^ nsw) * 8;
        bf16x8 b0 = ld_bf8(r0 + gp);
        bf16x8 b1 = ld_bf8(r1 + gp);
        sacc[0][0] = __builtin_amdgcn_mfma_f32_16x16x32_bf16(afr[0][kk], b0, sacc[0][0], 0, 0, 0);
        sacc[1][0] = __builtin_amdgcn_mfma_f32_16x16x32_bf16(afr[1][kk], b0, sacc[1][0], 0, 0, 0);
        sacc[0][1] = __builtin_amdgcn_mfma_f32_16x16x32_bf16(afr[0][kk], b1, sacc[0][1], 0, 0, 0);
        sacc[1][1] = __builtin_amdgcn_mfma_f32_16x16x32_bf16(afr[1][kk], b1, sacc[1][1], 0, 0, 0);
      }
    }

    // ---- partial row max over this wave's 32 j
#pragma unroll
    for (int it2 = 0; it2 < 2; ++it2) {
      float pm[4];
#pragma unroll
      for (int r = 0; r < 4; ++r) {
        float tm = fmaxf(sacc[it2][0][r], sacc[it2][1][r]);
        tm = fmaxf(tm, __shfl_xor(tm, 1));
        tm = fmaxf(tm, __shfl_xor(tm, 2));
        tm = fmaxf(tm, __shfl_xor(tm, 4));
        tm = fmaxf(tm, __shfl_xor(tm, 8));
        pm[r] = tm;
      }
      if (n == 0) {
#pragma unroll
        for (int r = 0; r < 4; ++r)
          pstat[(ig * 32 + it2 * 16 + q4 * 4 + r) * 2 + jh] = pm[r];
      }
    }

    WAIT_LGKM0();
    BAR_RAW();      // BAR B: both halves' partial maxima visible

    // ---- combine maxima, exp2, write P + alpha
#pragma unroll
    for (int it2 = 0; it2 < 2; ++it2) {
#pragma unroll
      for (int r = 0; r < 4; ++r) {
        const int i = ig * 32 + it2 * 16 + q4 * 4 + r;
        const f32x2 pp = *reinterpret_cast<const f32x2*>(&pstat[i * 2]);   // broadcast
        const float tm = fmaxf(pp[0], pp[1]);
        const float mnew = fmaxf(mrow[it2][r], tm);
        const float a = __builtin_amdgcn_exp2f(mrow[it2][r] - mnew);
        mrow[it2][r] = mnew;
        if (jh == 0 && n == 0) stat_lds[i] = a;
        const int r7 = i & 7;
#pragma unroll
        for (int jt2 = 0; jt2 < 2; ++jt2) {
          const float p = __builtin_amdgcn_exp2f(sacc[it2][jt2][r] - mnew);
          const int chunk = jh * 4 + jt2 * 2 + (n >> 3);
          pbuf[i * 64 + (chunk ^ r7) * 8 + nsw] = f2bf(p);
        }
      }
    }

    // ---- issue V chunk1 (ct 0,1) -- live only into PV pass 1
    CFENCE();
    i32x4 vA[4];
#pragma unroll
    for (int ct = 0; ct < 2; ++ct) {
      const unsigned short* vp = vb + (size_t)(w * 64 + ct * 16 + n) * NPOS + j0 + q4 * 8;
      vA[ct * 2]     = *reinterpret_cast<const i32x4*>(vp);
      vA[ct * 2 + 1] = *reinterpret_cast<const i32x4*>(vp + 32);
    }

    WAIT_LGKM0();   // my P/stat ds_writes landed (doesn't touch vmem)
    BAR_RAW();      // BAR C: P + alpha visible to all

    // ---- PV prep: alpha, P fragments (all 8, read once), l via ones-MFMA
    float al[4];
#pragma unroll
    for (int it = 0; it < 4; ++it) al[it] = stat_lds[it * 16 + n];

    bf16x8 pf[8];
#pragma unroll
    for (int it = 0; it < 4; ++it) {
      const int rw = it * 16 + n;
      const int r7 = rw & 7;
      pf[it * 2 + 0] = ld_bf8(&pbuf[rw * 64 + ((q4) ^ r7) * 8]);
      pf[it * 2 + 1] = ld_bf8(&pbuf[rw * 64 + ((4 + q4) ^ r7) * 8]);
    }

#pragma unroll
    for (int it = 0; it < 4; ++it) {
#pragma unroll
      for (int ct = 0; ct < 4; ++ct) {
        f32x4& o = O[ct * 4 + it];
        o[0] *= al[it]; o[1] *= al[it]; o[2] *= al[it]; o[3] *= al[it];
      }
    }
    lacc[0] *= al[w]; lacc[1] *= al[w]; lacc[2] *= al[w]; lacc[3] *= al[w];
    lacc = __builtin_amdgcn_mfma_f32_16x16x32_bf16(ones, pf[w * 2 + 0], lacc, 0, 0, 0);
    lacc = __builtin_amdgcn_mfma_f32_16x16x32_bf16(ones, pf[w * 2 + 1], lacc, 0, 0, 0);

    // ---- PV pass 1: ct 0,1 from vA
#pragma unroll
    for (int ct = 0; ct < 2; ++ct) {
      bf16x8 vf0 = __builtin_bit_cast(bf16x8, vA[ct * 2]);
      bf16x8 vf1 = __builtin_bit_cast(bf16x8, vA[ct * 2 + 1]);
#pragma unroll
      for (int it = 0; it < 4; ++it) {
        O[ct * 4 + it] = __builtin_amdgcn_mfma_f32_16x16x32_bf16(vf0, pf[it * 2 + 0], O[ct * 4 + it], 0, 0, 0);
        O[ct * 4 + it] = __builtin_amdgcn_mfma_f32_16x16x32_bf16(vf1, pf[it * 2 + 1], O[ct * 4 + it], 0, 0, 0);
      }
    }

    // ---- issue V chunk2 (ct 2,3), THEN K[jt+1] DMA (order keeps vmcnt clean:
    // chunk2 retires at vmcnt(8), leaving the 8 DMA ops in flight)
    CFENCE();
#pragma unroll
    for (int ct = 0; ct < 2; ++ct) {
      const unsigned short* vp = vb + (size_t)(w * 64 + (ct + 2) * 16 + n) * NPOS + j0 + q4 * 8;
      vA[ct * 2]     = *reinterpret_cast<const i32x4*>(vp);
      vA[ct * 2 + 1] = *reinterpret_cast<const i32x4*>(vp + 32);
    }
    CFENCE();
    {
      const int j0n = ((jt + 1) & 63) * 64;
      unsigned short* bufn = kbuf[(jt + 1) & 1];
#pragma unroll
      for (int it = 0; it < 8; ++it) {
        const int t = w * 8 + it;
        const int j = 2 * t + (l >> 5);
        const int gp = l & 31;
        const int g  = gp ^ (j & 7);
        const unsigned short* src = kTb + (size_t)(j0n + j) * CCH + g * 8;
        unsigned short* dst = &bufn[t * 512];
        __builtin_amdgcn_global_load_lds((GAS*)src, (LAS*)dst, 16, 0, 0);
      }
    }
    CFENCE();

    // ---- PV pass 2: ct 2,3 from vA (compiler waits vmcnt(8), DMA stays in flight)
#pragma unroll
    for (int ct = 2; ct < 4; ++ct) {
      bf16x8 vf0 = __builtin_bit_cast(bf16x8, vA[(ct - 2) * 2]);
      bf16x8 vf1 = __builtin_bit_cast(bf16x8, vA[(ct - 2) * 2 + 1]);
#pragma unroll
      for (int it = 0; it < 4; ++it) {
        O[ct * 4 + it] = __builtin_amdgcn_mfma_f32_16x16x32_bf16(vf0, pf[it * 2 + 0], O[ct * 4 + it], 0, 0, 0);
        O[ct * 4 + it] = __builtin_amdgcn_mfma_f32_16x16x32_bf16(vf1, pf[it * 2 + 1], O[ct * 4 + it], 0, 0, 0);
      }
    }
  }

  // ---- epilogue: y = x + gamma * O / l
  __syncthreads();
  if (q4 == 0) stat_lds[w * 16 + n] = lacc[0];
  __syncthreads();
  const float g = gamma[0];
#pragma unroll
  for (int it = 0; it < 4; ++it) {
    const float sc = g / stat_lds[it * 16 + n];
    const int ipos = i0 + it * 16 + n;
#pragma unroll
    for (int ct = 0; ct < 4; ++ct) {
#pragma unroll
      for (int r = 0; r < 4; ++r) {
        const int c = w * 64 + ct * 16 + q4 * 4 + r;
        const size_t idx = ((size_t)(b * CCH + c)) * NPOS + ipos;
        out[idx] = x[idx] + sc * O[ct * 4 + it][r];
      }
    }
  }
}

// ---------------------------------------------------------------- launch
extern "C" void kernel_launch(void* const* d_in, const int* in_sizes, int n_in,
                              void* d_out, int out_size, void* d_ws, size_t ws_size,
                              hipStream_t stream)
{
  const float* x     = (const float*)d_in[0];
  const float* Wq    = (const float*)d_in[1];
  const float* bq    = (const float*)d_in[2];
  const float* Wk    = (const float*)d_in[3];
  const float* bk    = (const float*)d_in[4];
  const float* Wv    = (const float*)d_in[5];
  const float* bv    = (const float*)d_in[6];
  const float* gamma = (const float*)d_in[7];
  float* out = (float*)d_out;

  unsigned short* ws   = (unsigned short*)d_ws;
  unsigned short* Wall = ws;                                  // 3 x 65536 bf16
  unsigned short* qT   = ws + 196608;                         // (B,N,C) bf16
  unsigned short* kT   = qT + (size_t)BATCH * NPOS * CCH;     // (B,N,C) bf16
  unsigned short* vG   = kT + (size_t)BATCH * NPOS * CCH;     // (B,C,N) bf16

  cvt_kernel<<<768, 256, 0, stream>>>(Wq, Wk, Wv, Wall);
  qkv_kernel<<<dim3(8, 64), 256, 0, stream>>>(x, Wall, bq, bk, bv, qT, kT, vG);
  attn_kernel<<<dim3(8, 64), 256, 0, stream>>>(qT, kT, vG, x, gamma, out);
}

// Round 7
// 888.817 us; speedup vs baseline: 1.8487x; 1.7365x over previous
//
#include <hip/hip_runtime.h>

#define BATCH 8
#define CCH 256
#define NPOS 4096
#define LOG2E 1.4426950408889634f

typedef __bf16 bf16x8 __attribute__((ext_vector_type(8)));
typedef float f32x4 __attribute__((ext_vector_type(4)));
typedef int i32x4 __attribute__((ext_vector_type(4)));
typedef unsigned short us4 __attribute__((ext_vector_type(4)));

typedef const __attribute__((address_space(1))) void GAS;
typedef __attribute__((address_space(3))) void LAS;

#define CFENCE() __asm__ volatile("" ::: "memory")
// vmcnt(0), lgkm no-wait(15), exp no-wait(7)
#define WAIT_VM0()  do { CFENCE(); __builtin_amdgcn_s_waitcnt(0x0F70); CFENCE(); } while (0)
// lgkmcnt(0), vmcnt no-wait(63), exp no-wait
#define WAIT_LGKM0() do { CFENCE(); __builtin_amdgcn_s_waitcnt(0xC07F); CFENCE(); } while (0)
#define BAR_RAW() do { CFENCE(); __builtin_amdgcn_s_barrier(); CFENCE(); } while (0)

__device__ __forceinline__ unsigned short f2bf(float f) {
  unsigned u = __builtin_bit_cast(unsigned, f);
  u += 0x7fffu + ((u >> 16) & 1u);
  return (unsigned short)(u >> 16);
}
__device__ __forceinline__ bf16x8 ld_bf8(const unsigned short* p) {
  i32x4 t = *reinterpret_cast<const i32x4*>(p);
  return __builtin_bit_cast(bf16x8, t);
}

// ---------------------------------------------------------------- kernel 1
__global__ void cvt_kernel(const float* __restrict__ Wq,
                           const float* __restrict__ Wk,
                           const float* __restrict__ Wv,
                           unsigned short* __restrict__ dst)
{
  const int idx = blockIdx.x * 256 + threadIdx.x;   // 0..196607
  const float* src = (idx < 65536) ? Wq : ((idx < 131072) ? Wk : Wv);
  float v = src[idx & 65535];
  if (idx < 65536) v *= LOG2E;      // fold log2e into Q projection (exp2 softmax)
  dst[idx] = f2bf(v);
}

// ---------------------------------------------------------------- kernel 2
// One block per (b, 64-pos tile); z-loop over 4 o-phases reuses staged xT.
// (R3-measured: cvt+qkv ~57 us)
__global__ __launch_bounds__(256, 3)
void qkv_kernel(const float* __restrict__ x,
                const unsigned short* __restrict__ Wall,   // Wq*log2e|Wk|Wv bf16
                const float* __restrict__ bq,
                const float* __restrict__ bk,
                const float* __restrict__ bv,
                unsigned short* __restrict__ qT,
                unsigned short* __restrict__ kT,
                unsigned short* __restrict__ vG)
{
  __shared__ __align__(16) unsigned short xT[64 * 264];   // 33792 B
  __shared__ __align__(16) unsigned short tbuf[64 * 72];  //  9216 B (v transpose)

  const int b   = blockIdx.x;
  const int i0  = blockIdx.y * 64;
  const int tid = threadIdx.x;
  const int w   = tid >> 6;
  const int l   = tid & 63;
  const int n   = l & 15;
  const int q4  = l >> 4;

  {
    const float* xp = x + ((size_t)b * CCH + tid) * NPOS + i0;
#pragma unroll
    for (int it = 0; it < 16; ++it) {
      f32x4 f = *reinterpret_cast<const f32x4*>(xp + it * 4);
#pragma unroll
      for (int e = 0; e < 4; ++e) xT[(it * 4 + e) * 264 + tid] = f2bf(f[e]);
    }
  }
  __syncthreads();

  const size_t qbase = (size_t)b * NPOS * CCH;

  for (int z = 0; z < 4; ++z) {
    const int obase = z * 64;
    for (int s = 0; s < 3; ++s) {
      const unsigned short* Wp = Wall + s * 65536 + (size_t)(obase + w * 16 + n) * CCH + q4 * 8;
      bf16x8 wfr[8];
#pragma unroll
      for (int kk = 0; kk < 8; ++kk) wfr[kk] = ld_bf8(Wp + kk * 32);

      const float* bias = (s == 0) ? bq : (s == 1) ? bk : bv;
      const float bscale = (s == 0) ? LOG2E : 1.0f;
      float bo[4];
#pragma unroll
      for (int r = 0; r < 4; ++r) bo[r] = bias[obase + w * 16 + q4 * 4 + r] * bscale;

      f32x4 acc[4];
#pragma unroll
      for (int pt = 0; pt < 4; ++pt) {
        acc[pt] = {0.f, 0.f, 0.f, 0.f};
#pragma unroll
        for (int kk = 0; kk < 8; ++kk) {
          bf16x8 bfr = ld_bf8(&xT[(pt * 16 + n) * 264 + kk * 32 + q4 * 8]);
          acc[pt] = __builtin_amdgcn_mfma_f32_16x16x32_bf16(wfr[kk], bfr, acc[pt], 0, 0, 0);
        }
      }

      if (s < 2) {
        unsigned short* dst = (s == 0 ? qT : kT) + qbase;
#pragma unroll
        for (int pt = 0; pt < 4; ++pt) {
          us4 pk = { f2bf(acc[pt][0] + bo[0]), f2bf(acc[pt][1] + bo[1]),
                     f2bf(acc[pt][2] + bo[2]), f2bf(acc[pt][3] + bo[3]) };
          *reinterpret_cast<us4*>(&dst[(size_t)(i0 + pt * 16 + n) * CCH + obase + w * 16 + q4 * 4]) = pk;
        }
      } else {
        __syncthreads();   // tbuf free (previous z's v-store consumed it)
#pragma unroll
        for (int pt = 0; pt < 4; ++pt)
#pragma unroll
          for (int r = 0; r < 4; ++r)
            tbuf[(w * 16 + q4 * 4 + r) * 72 + pt * 16 + n] = f2bf(acc[pt][r] + bo[r]);
        __syncthreads();
#pragma unroll
        for (int it = 0; it < 2; ++it) {
          const int idx = it * 256 + tid;
          const int o = idx >> 3, pw = (idx & 7) * 8;
          i32x4 d = *reinterpret_cast<const i32x4*>(&tbuf[o * 72 + pw]);
          *reinterpret_cast<i32x4*>(&vG[qbase + (size_t)(obase + o) * NPOS + i0 + pw]) = d;
        }
      }
    }
  }
}

// ---------------------------------------------------------------- kernel 3
// Flash attention, Br=64, Bc=64, 4 waves. R7 = R2 partition (wave owns 16
// full rows in S -> afr[8]=32 VGPRs only, NO cross-wave max exchange,
// 2 barriers/iter) + the verified cheap wins:
//  - exp2-domain softmax (log2e folded into Wq/bq)
//  - l via ones-MFMA (no shfl-sum chain)
//  - XOR-swizzled pbuf, direct u16 writes (R2's 2.1e7 conflicts were shfl-pack)
//  - V just-in-time 2-chunk loads inside PV (not live across S)
//  - K DMA double-buffer, prefetch issued mid-PV (vmcnt order keeps it in flight)
// Register peak ~105 arch VGPRs -- R2's proven-clean envelope (R4/R6 lesson:
// 128 arch is the practical cap at 2-wave occupancy with 64+ AGPRs of O).
__global__ __launch_bounds__(256, 2)
void attn_kernel(const unsigned short* __restrict__ qT,
                 const unsigned short* __restrict__ kT,
                 const unsigned short* __restrict__ vG,
                 const float* __restrict__ x,
                 const float* __restrict__ gamma,
                 float* __restrict__ out)
{
  __shared__ __align__(16) unsigned short kbuf[2][64 * 256];  // 2 x 32768 B, swizzled
  __shared__ __align__(16) unsigned short pbuf[64 * 64];      //  8192 B, swizzled
  __shared__ float stat_lds[64];                              //  alpha / l broadcast

  const int b   = blockIdx.x;
  const int i0  = blockIdx.y * 64;
  const int tid = threadIdx.x;
  const int w   = tid >> 6;
  const int l   = tid & 63;
  const int n   = l & 15;
  const int q4  = l >> 4;
  const int nsw = n & 7;

  const unsigned short* qTb = qT + (size_t)b * NPOS * CCH;
  const unsigned short* kTb = kT + (size_t)b * NPOS * CCH;
  const unsigned short* vb  = vG + (size_t)b * NPOS * CCH;

  // Q fragments register-resident: wave w owns i rows [w*16, +16) = 32 VGPRs
  bf16x8 afr[8];
  {
    const unsigned short* qrow = qTb + (size_t)(i0 + w * 16 + n) * CCH + q4 * 8;
#pragma unroll
    for (int kk = 0; kk < 8; ++kk) afr[kk] = ld_bf8(qrow + kk * 32);
  }
  bf16x8 ones;
  {
    i32x4 t = { (int)0x3F803F80, (int)0x3F803F80, (int)0x3F803F80, (int)0x3F803F80 };
    ones = __builtin_bit_cast(bf16x8, t);
  }

  // stage K[0] DMA; instr t covers local rows 2t,2t+1; phys granule gp at
  // row j holds logical granule gp ^ (j&7)
#pragma unroll
  for (int it = 0; it < 8; ++it) {
    const int t = w * 8 + it;
    const int j = 2 * t + (l >> 5);
    const int gp = l & 31;
    const int g  = gp ^ (j & 7);
    const unsigned short* src = kTb + (size_t)j * CCH + g * 8;
    unsigned short* dst = &kbuf[0][t * 512];
    __builtin_amdgcn_global_load_lds((GAS*)src, (LAS*)dst, 16, 0, 0);
  }

  f32x4 O[16];   // [ct*4+it]: c in [w*64+ct*16,+16), i in [it*16,+16)
#pragma unroll
  for (int t = 0; t < 16; ++t) O[t] = {0.f, 0.f, 0.f, 0.f};
  f32x4 lacc = {0.f, 0.f, 0.f, 0.f};
  float mrow[4] = {-1e30f, -1e30f, -1e30f, -1e30f};

  for (int jt = 0; jt < 64; ++jt) {
    const int j0 = jt * 64;
    const unsigned short* kb = kbuf[jt & 1];

    WAIT_VM0();     // only K[jt] DMA is in flight here -> exact drain
    BAR_RAW();      // BAR A: K[jt] in LDS for all; pbuf/stat consumed (prev PV)

    // ---- S = Q K^T: wave w computes i in [w*16,+16) x all 64 j
    // swizzled K reads: phys granule = (kk*4+q4) ^ (n&7)
    f32x4 sacc[4];
#pragma unroll
    for (int nt = 0; nt < 4; ++nt) {
      const unsigned short* krow = kb + (nt * 16 + n) * 256;
      sacc[nt] = {0.f, 0.f, 0.f, 0.f};
#pragma unroll
      for (int kk = 0; kk < 8; ++kk) {
        const int gp = (kk * 4 + q4) ^ nsw;
        bf16x8 bfr = ld_bf8(krow + gp * 8);
        sacc[nt] = __builtin_amdgcn_mfma_f32_16x16x32_bf16(afr[kk], bfr, sacc[nt], 0, 0, 0);
      }
    }

    // ---- online softmax: full row in-wave (row = w*16 + q4*4 + r),
    // 16-lane max reduce; sum comes from ones-MFMA later
    float a_r[4];
#pragma unroll
    for (int r = 0; r < 4; ++r) {
      float tm = fmaxf(fmaxf(sacc[0][r], sacc[1][r]), fmaxf(sacc[2][r], sacc[3][r]));
      tm = fmaxf(tm, __shfl_xor(tm, 1));
      tm = fmaxf(tm, __shfl_xor(tm, 2));
      tm = fmaxf(tm, __shfl_xor(tm, 4));
      tm = fmaxf(tm, __shfl_xor(tm, 8));
      const float mnew = fmaxf(mrow[r], tm);
      a_r[r] = __builtin_amdgcn_exp2f(mrow[r] - mnew);
      mrow[r] = mnew;
#pragma unroll
      for (int nt = 0; nt < 4; ++nt)
        sacc[nt][r] = __builtin_amdgcn_exp2f(sacc[nt][r] - mnew);
    }

    if (n == 0) {
#pragma unroll
      for (int r = 0; r < 4; ++r) stat_lds[w * 16 + q4 * 4 + r] = a_r[r];
    }
    // P -> pbuf, XOR-swizzled: phys = i*64 + ((j>>3)^(i&7))*8 + (j&7)
#pragma unroll
    for (int r = 0; r < 4; ++r) {
      const int i = w * 16 + q4 * 4 + r;
      const int r7 = i & 7;
#pragma unroll
      for (int nt = 0; nt < 4; ++nt) {
        const int chunk = nt * 2 + (n >> 3);
        pbuf[i * 64 + (chunk ^ r7) * 8 + nsw] = f2bf(sacc[nt][r]);
      }
    }

    // ---- issue V chunk1 (ct 0,1) -- live only into PV pass 1
    CFENCE();
    i32x4 vA[4];
#pragma unroll
    for (int ct = 0; ct < 2; ++ct) {
      const unsigned short* vp = vb + (size_t)(w * 64 + ct * 16 + n) * NPOS + j0 + q4 * 8;
      vA[ct * 2]     = *reinterpret_cast<const i32x4*>(vp);
      vA[ct * 2 + 1] = *reinterpret_cast<const i32x4*>(vp + 32);
    }

    WAIT_LGKM0();   // my P/stat ds_writes landed
    BAR_RAW();      // BAR B: P + alpha visible to all

    // ---- PV prep: alpha, P fragments, l via ones-MFMA
    float al[4];
#pragma unroll
    for (int it = 0; it < 4; ++it) al[it] = stat_lds[it * 16 + n];

    bf16x8 pf[8];
#pragma unroll
    for (int it = 0; it < 4; ++it) {
      const int rw = it * 16 + n;
      const int r7 = rw & 7;
      pf[it * 2 + 0] = ld_bf8(&pbuf[rw * 64 + ((q4) ^ r7) * 8]);
      pf[it * 2 + 1] = ld_bf8(&pbuf[rw * 64 + ((4 + q4) ^ r7) * 8]);
    }

#pragma unroll
    for (int it = 0; it < 4; ++it) {
#pragma unroll
      for (int ct = 0; ct < 4; ++ct) {
        f32x4& o = O[ct * 4 + it];
        o[0] *= al[it]; o[1] *= al[it]; o[2] *= al[it]; o[3] *= al[it];
      }
    }
    lacc[0] *= al[w]; lacc[1] *= al[w]; lacc[2] *= al[w]; lacc[3] *= al[w];
    lacc = __builtin_amdgcn_mfma_f32_16x16x32_bf16(ones, pf[w * 2 + 0], lacc, 0, 0, 0);
    lacc = __builtin_amdgcn_mfma_f32_16x16x32_bf16(ones, pf[w * 2 + 1], lacc, 0, 0, 0);

    // ---- PV pass 1: ct 0,1 from vA
#pragma unroll
    for (int ct = 0; ct < 2; ++ct) {
      bf16x8 vf0 = __builtin_bit_cast(bf16x8, vA[ct * 2]);
      bf16x8 vf1 = __builtin_bit_cast(bf16x8, vA[ct * 2 + 1]);
#pragma unroll
      for (int it = 0; it < 4; ++it) {
        O[ct * 4 + it] = __builtin_amdgcn_mfma_f32_16x16x32_bf16(vf0, pf[it * 2 + 0], O[ct * 4 + it], 0, 0, 0);
        O[ct * 4 + it] = __builtin_amdgcn_mfma_f32_16x16x32_bf16(vf1, pf[it * 2 + 1], O[ct * 4 + it], 0, 0, 0);
      }
    }

    // ---- issue V chunk2 (ct 2,3), THEN K[jt+1] DMA (vmcnt order: chunk2
    // retires at vmcnt(8), leaving the 8 DMA ops in flight across iter end)
    CFENCE();
#pragma unroll
    for (int ct = 0; ct < 2; ++ct) {
      const unsigned short* vp = vb + (size_t)(w * 64 + (ct + 2) * 16 + n) * NPOS + j0 + q4 * 8;
      vA[ct * 2]     = *reinterpret_cast<const i32x4*>(vp);
      vA[ct * 2 + 1] = *reinterpret_cast<const i32x4*>(vp + 32);
    }
    CFENCE();
    {
      const int j0n = ((jt + 1) & 63) * 64;   // unconditional, wrapped
      unsigned short* bufn = kbuf[(jt + 1) & 1];
#pragma unroll
      for (int it = 0; it < 8; ++it) {
        const int t = w * 8 + it;
        const int j = 2 * t + (l >> 5);
        const int gp = l & 31;
        const int g  = gp ^ (j & 7);
        const unsigned short* src = kTb + (size_t)(j0n + j) * CCH + g * 8;
        unsigned short* dst = &bufn[t * 512];
        __builtin_amdgcn_global_load_lds((GAS*)src, (LAS*)dst, 16, 0, 0);
      }
    }
    CFENCE();

    // ---- PV pass 2: ct 2,3 from vA
#pragma unroll
    for (int ct = 2; ct < 4; ++ct) {
      bf16x8 vf0 = __builtin_bit_cast(bf16x8, vA[(ct - 2) * 2]);
      bf16x8 vf1 = __builtin_bit_cast(bf16x8, vA[(ct - 2) * 2 + 1]);
#pragma unroll
      for (int it = 0; it < 4; ++it) {
        O[ct * 4 + it] = __builtin_amdgcn_mfma_f32_16x16x32_bf16(vf0, pf[it * 2 + 0], O[ct * 4 + it], 0, 0, 0);
        O[ct * 4 + it] = __builtin_amdgcn_mfma_f32_16x16x32_bf16(vf1, pf[it * 2 + 1], O[ct * 4 + it], 0, 0, 0);
      }
    }
  }

  // ---- epilogue: y = x + gamma * O / l
  __syncthreads();
  if (q4 == 0) stat_lds[w * 16 + n] = lacc[0];
  __syncthreads();
  const float g = gamma[0];
#pragma unroll
  for (int it = 0; it < 4; ++it) {
    const float sc = g / stat_lds[it * 16 + n];
    const int ipos = i0 + it * 16 + n;
#pragma unroll
    for (int ct = 0; ct < 4; ++ct) {
#pragma unroll
      for (int r = 0; r < 4; ++r) {
        const int c = w * 64 + ct * 16 + q4 * 4 + r;
        const size_t idx = ((size_t)(b * CCH + c)) * NPOS + ipos;
        out[idx] = x[idx] + sc * O[ct * 4 + it][r];
      }
    }
  }
}

// ---------------------------------------------------------------- launch
extern "C" void kernel_launch(void* const* d_in, const int* in_sizes, int n_in,
                              void* d_out, int out_size, void* d_ws, size_t ws_size,
                              hipStream_t stream)
{
  const float* x     = (const float*)d_in[0];
  const float* Wq    = (const float*)d_in[1];
  const float* bq    = (const float*)d_in[2];
  const float* Wk    = (const float*)d_in[3];
  const float* bk    = (const float*)d_in[4];
  const float* Wv    = (const float*)d_in[5];
  const float* bv    = (const float*)d_in[6];
  const float* gamma = (const float*)d_in[7];
  float* out = (float*)d_out;

  unsigned short* ws   = (unsigned short*)d_ws;
  unsigned short* Wall = ws;                                  // 3 x 65536 bf16
  unsigned short* qT   = ws + 196608;                         // (B,N,C) bf16
  unsigned short* kT   = qT + (size_t)BATCH * NPOS * CCH;     // (B,N,C) bf16
  unsigned short* vG   = kT + (size_t)BATCH * NPOS * CCH;     // (B,C,N) bf16

  cvt_kernel<<<768, 256, 0, stream>>>(Wq, Wk, Wv, Wall);
  qkv_kernel<<<dim3(8, 64), 256, 0, stream>>>(x, Wall, bq, bk, bv, qT, kT, vG);
  attn_kernel<<<dim3(8, 64), 256, 0, stream>>>(qT, kT, vG, x, gamma, out);
}